// Round 8
// baseline (215.824 us; speedup 1.0000x reference)
//
#include <hip/hip_runtime.h>
#include <stdint.h>

namespace {

typedef short bf16x8 __attribute__((ext_vector_type(8)));
typedef float f32x16 __attribute__((ext_vector_type(16)));
typedef unsigned short u16x4 __attribute__((ext_vector_type(4)));

constexpr int BATCH = 16;
constexpr int LQ = 2048;
constexpr int LK = 2048;
constexpr int DIM = 64;
constexpr float SCALE = 0.125f;  // 1/sqrt(64)

// d_ws byte offsets (flag at 0)
constexpr size_t WS_KHI = 1ull << 20;   // 4 MB bf16 K-hi, fragment-ordered
constexpr size_t WS_KLO = 6ull << 20;   // 4 MB bf16 K-lo
constexpr size_t WS_VT = 11ull << 20;   // 4 MB bf16 V, fragment-ordered

__global__ void detect_mask_dtype(const uint32_t* __restrict__ mask,
                                  int* __restrict__ flag) {
  __shared__ int bad;
  if (threadIdx.x == 0) bad = 0;
  __syncthreads();
  int my = 0;
  for (int i = threadIdx.x; i < 4096; i += 256) {
    uint32_t w = mask[i];
    if (w > 1u && w != 0x3F800000u) my = 1;
  }
  if (my) atomicOr(&bad, 1);
  __syncthreads();
  if (threadIdx.x == 0) *flag = bad;  // 1 -> uint8-packed
}

__device__ inline unsigned short f2bf(float x) {  // RNE fp32->bf16
  union { float f; unsigned u; } c;
  c.f = x;
  unsigned r = c.u + 0x7FFFu + ((c.u >> 16) & 1u);
  return (unsigned short)(r >> 16);
}
__device__ inline float bf2f(unsigned short h) {
  union { float f; unsigned u; } c;
  c.u = (unsigned)h << 16;
  return c.f;
}
__device__ inline int cvt_pk_bf16(float lo, float hi) {
  int d;
  asm("v_cvt_pk_bf16_f32 %0, %1, %2" : "=v"(d) : "v"(lo), "v"(hi));
  return d;
}

// mfma_f32_32x32x16_bf16 layouts:
//   A: m=l&31, k=(l>>5)*8+e      B: n=l&31, k=(l>>5)*8+e   (16x16 family
//   pattern at 32 lanes; 4 VGPR = 8 bf16)
//   C/D: col n=l&31, row m=crow(reg,l>>5)=(reg&3)+8*(reg>>2)+4*(l>>5)
//   [C/D verified m74/m101]

// K -> fragment-ordered: [b][T][f][s][lane][8]  lane=hi*32+m,
// element e at d = s*16+hi*8+e, row k~ = T*64 + f*32 + m.
__global__ __launch_bounds__(256) void prep_k(const float* __restrict__ kp,
                                              unsigned short* __restrict__ khi,
                                              unsigned short* __restrict__ klo) {
  int idx = blockIdx.x * 256 + threadIdx.x;  // 16*2048*16
  int b = idx >> 15;
  int rem = idx & 32767;
  int r = rem >> 4;          // row in batch
  int d0 = (rem & 15) * 4;   // d quad
  float4 kf = *(const float4*)(kp + ((size_t)b * LK + r) * DIM + d0);
  u16x4 hv, lv;
#pragma unroll
  for (int j = 0; j < 4; ++j) {
    float x = (&kf.x)[j];
    unsigned short hh = f2bf(x);
    hv[j] = hh;
    lv[j] = f2bf(x - bf2f(hh));
  }
  int T = r >> 6;
  int rin = r & 63;
  int f = rin >> 5;
  int m = rin & 31;
  int s = d0 >> 4;
  int hi = (d0 >> 3) & 1;
  int e0 = d0 & 7;
  size_t off = ((((size_t)(b * 32 + T) * 2 + f) * 4 + s) * 64 +
                (hi * 32 + m)) * 8 + e0;
  *(u16x4*)(khi + off) = hv;
  *(u16x4*)(klo + off) = lv;
}

// V -> fragment-ordered: [b][T][nb][ks][lane][8]  lane=hi*32+(d&31),
// element e at k~in = ks*16+hi*8+e, col d = nb*32 + (d&31).
__global__ __launch_bounds__(256) void prep_v(const float* __restrict__ vp,
                                              unsigned short* __restrict__ vt) {
  int idx = blockIdx.x * 256 + threadIdx.x;  // 16*512*16
  int b = idx >> 13;
  int rem = idx & 8191;
  int kq = rem >> 4;
  int dq = rem & 15;
  int k0 = kq * 4;
  int T = k0 >> 6;
  int kin = k0 & 63;
  const float* vg = vp + ((size_t)b * LK + k0) * DIM + dq * 4;
  unsigned short tmp[4][4];
#pragma unroll
  for (int j = 0; j < 4; ++j) {
    float4 vf = *(const float4*)(vg + j * DIM);
#pragma unroll
    for (int i2 = 0; i2 < 4; ++i2) tmp[j][i2] = f2bf((&vf.x)[i2]);
  }
  int ks = kin >> 4;
  int hi = (kin >> 3) & 1;
  int e0 = kin & 7;  // 0 or 4
#pragma unroll
  for (int j2 = 0; j2 < 4; ++j2) {
    int d = dq * 4 + j2;
    int nb = d >> 5;
    u16x4 od = {tmp[0][j2], tmp[1][j2], tmp[2][j2], tmp[3][j2]};
    size_t off = ((((size_t)(b * 32 + T) * 2 + nb) * 4 + ks) * 64 +
                  (hi * 32 + (d & 31))) * 8 + e0;
    *(u16x4*)(vt + off) = od;
  }
}

// Main kernel: 4 waves/block, wave = (wq = q-subtile of 32 rows, h = k-half).
// No LDS, no barriers in the main loop. K/V read fragment-ordered from L2.
__global__ __launch_bounds__(256, 2) void attn_mfma(
    const float* __restrict__ qp, const unsigned short* __restrict__ khi_f,
    const unsigned short* __restrict__ klo_f,
    const unsigned short* __restrict__ vt_f,
    const uint32_t* __restrict__ maskp, const int* __restrict__ flagp,
    float* __restrict__ out) {
  __shared__ float X[2 * 64 * 33];    // h-combine scratch
  __shared__ float den_lds[2 * 32];   // per-wq inverse denominators

  const int tid = threadIdx.x;
  const int w = tid >> 6;
  const int l = tid & 63;
  const int m31 = l & 31;
  const int hi = l >> 5;
  const int wq = w >> 1;
  const int h = w & 1;
  // XCD swizzle: 2 batches per XCD -> K/V frag arrays (1.6 MB) L2-resident.
  const int xcd = blockIdx.x & 7;
  const int idx = blockIdx.x >> 3;
  const int b = xcd * 2 + (idx >> 5);
  const int qbase = (idx & 31) * 64;
  const int isU8 = *flagp;
  const int qrow = qbase + wq * 32 + m31;

  // ---- Q fragments (hi/lo split), B-operand: n=q-row, k=d ----
  bf16x8 qh[4], ql[4];
  {
    const float* qr = qp + ((size_t)b * LQ + qrow) * DIM;
#pragma unroll
    for (int s = 0; s < 4; ++s) {
#pragma unroll
      for (int j2 = 0; j2 < 2; ++j2) {
        float4 x = *(const float4*)(qr + s * 16 + hi * 8 + j2 * 4);
#pragma unroll
        for (int j = 0; j < 4; ++j) {
          float xv = (&x.x)[j];
          unsigned short hh = f2bf(xv);
          qh[s][j2 * 4 + j] = (short)hh;
          ql[s][j2 * 4 + j] = (short)f2bf(xv - bf2f(hh));
        }
      }
    }
  }

  const uint8_t* m8 = (const uint8_t*)maskp;
  uint4 pm[8];
  auto loadMask = [&](int T) {
    const int col0 = T * 64 + hi * 32;
    if (!isU8) {
      const uint32_t* mg = maskp + (size_t)qrow * LK + col0;
#pragma unroll
      for (int i = 0; i < 8; ++i) pm[i] = *(const uint4*)(mg + i * 4);
    } else {
      const uint8_t* mg = m8 + (size_t)qrow * LK + col0;
#pragma unroll
      for (int i = 0; i < 2; ++i) pm[i] = *(const uint4*)(mg + i * 16);
    }
  };
  // mask rows are per-batch: maskp indexed [b][q][k]
  const size_t mbase = (size_t)b * LQ * LK;
  auto loadMaskB = [&](int T) {
    const int col0 = T * 64 + hi * 32;
    if (!isU8) {
      const uint32_t* mg = maskp + mbase + (size_t)qrow * LK + col0;
#pragma unroll
      for (int i = 0; i < 8; ++i) pm[i] = *(const uint4*)(mg + i * 4);
    } else {
      const uint8_t* mg = m8 + mbase + (size_t)qrow * LK + col0;
#pragma unroll
      for (int i = 0; i < 2; ++i) pm[i] = *(const uint4*)(mg + i * 16);
    }
  };
  (void)loadMask;

  f32x16 acc_o[2];
#pragma unroll
  for (int nb = 0; nb < 2; ++nb) acc_o[nb] = (f32x16)(0.f);
  float den = 0.f;

  loadMaskB(h * 16);  // prologue mask prefetch

  for (int t = 0; t < 16; ++t) {
    const int T = h * 16 + t;
    // ---- pack this tile's mask half (32 cols) into 32 bits ----
    uint32_t m32 = 0;
    if (!isU8) {
#pragma unroll
      for (int i = 0; i < 8; ++i) {
        uint4 x = pm[i];
        uint32_t nib = (x.x != 0) | ((x.y != 0) << 1) | ((x.z != 0) << 2) |
                       ((x.w != 0) << 3);
        m32 |= nib << (4 * i);
      }
    } else {
#pragma unroll
      for (int i = 0; i < 2; ++i) {
        uint4 x = pm[i];
#pragma unroll
        for (int dd = 0; dd < 4; ++dd) {
          uint32_t wv = (&x.x)[dd];
          uint32_t nib = ((wv & 0xFFu) != 0) | (((wv >> 8) & 0xFFu) != 0) << 1 |
                         (((wv >> 16) & 0xFFu) != 0) << 2 |
                         (((wv >> 24) & 0xFFu) != 0) << 3;
          m32 |= nib << (i * 16 + dd * 4);
        }
      }
    }
    // full 64-bit row mask: other col-half from partner lane
    uint32_t other = (uint32_t)__shfl_xor((int)m32, 32);
    uint32_t bitsF[2];  // bitsF[f]: cols f*32..f*32+31 of this tile
    bitsF[hi] = m32;
    bitsF[hi ^ 1] = other;
    // ---- prefetch next tile's mask (flies across the whole compute) ----
    if (t < 15) loadMaskB(T + 1);

    // ---- swapped QK^T: S^T = K*Q^T, 3-term Ootomo split ----
    f32x16 acc_s[2];
    acc_s[0] = (f32x16)(0.f);
    acc_s[1] = (f32x16)(0.f);
#pragma unroll
    for (int f = 0; f < 2; ++f) {
#pragma unroll
      for (int s = 0; s < 4; ++s) {
        size_t off =
            ((((size_t)(b * 32 + T) * 2 + f) * 4 + s) * 64 + l) * 8;
        bf16x8 kh = *(const bf16x8*)(khi_f + off);
        bf16x8 kl = *(const bf16x8*)(klo_f + off);
        acc_s[f] = __builtin_amdgcn_mfma_f32_32x32x16_bf16(kh, qh[s],
                                                           acc_s[f], 0, 0, 0);
        acc_s[f] = __builtin_amdgcn_mfma_f32_32x32x16_bf16(kl, qh[s],
                                                           acc_s[f], 0, 0, 0);
        acc_s[f] = __builtin_amdgcn_mfma_f32_32x32x16_bf16(kh, ql[s],
                                                           acc_s[f], 0, 0, 0);
      }
    }

    // ---- mask + exp in-register (lane owns q-col l&31, rows crow(reg,hi)) --
    const int hi4 = hi * 4;
#pragma unroll
    for (int f = 0; f < 2; ++f) {
      uint32_t bf_ = bitsF[f];
#pragma unroll
      for (int reg = 0; reg < 16; ++reg) {
        const int crow = (reg & 3) + 8 * (reg >> 2);
        uint32_t bit = (bf_ >> (crow + hi4)) & 1u;
        float e = bit ? 1.0f : __expf(acc_s[f][reg] * SCALE);
        den += e;
        acc_s[f][reg] = e;
      }
    }

    // ---- P -> A-frags via cvt_pk + permlane32_swap (m214 recipe) ----
#pragma unroll
    for (int f = 0; f < 2; ++f) {
#pragma unroll
      for (int a = 0; a < 2; ++a) {  // ks = f*2 + a
        int c0x = cvt_pk_bf16(acc_s[f][8 * a + 0], acc_s[f][8 * a + 1]);
        int c1x = cvt_pk_bf16(acc_s[f][8 * a + 2], acc_s[f][8 * a + 3]);
        int c0y = cvt_pk_bf16(acc_s[f][8 * a + 4], acc_s[f][8 * a + 5]);
        int c1y = cvt_pk_bf16(acc_s[f][8 * a + 6], acc_s[f][8 * a + 7]);
        asm("v_permlane32_swap_b32 %0, %1" : "+v"(c0x), "+v"(c0y));
        asm("v_permlane32_swap_b32 %0, %1" : "+v"(c1x), "+v"(c1y));
        union { int d[4]; bf16x8 v; } pa;
        pa.d[0] = c0x;
        pa.d[1] = c1x;
        pa.d[2] = c0y;
        pa.d[3] = c1y;
        const int ks = f * 2 + a;
#pragma unroll
        for (int nb = 0; nb < 2; ++nb) {
          size_t voff =
              ((((size_t)(b * 32 + T) * 2 + nb) * 4 + ks) * 64 + l) * 8;
          bf16x8 vb = *(const bf16x8*)(vt_f + voff);
          acc_o[nb] = __builtin_amdgcn_mfma_f32_32x32x16_bf16(pa.v, vb,
                                                              acc_o[nb], 0, 0, 0);
        }
      }
    }
  }

  // ---- epilogue: combine k-halves (waves wq*2 and wq*2+1) ----
  __syncthreads();
  if (h == 1) {
    float* xp = X + (wq * 64 + l) * 33;
#pragma unroll
    for (int nb = 0; nb < 2; ++nb)
#pragma unroll
      for (int reg = 0; reg < 16; ++reg) xp[nb * 16 + reg] = acc_o[nb][reg];
    xp[32] = den;
  }
  __syncthreads();
  if (h == 0) {
    const float* xp = X + (wq * 64 + l) * 33;
#pragma unroll
    for (int nb = 0; nb < 2; ++nb)
#pragma unroll
      for (int reg = 0; reg < 16; ++reg) acc_o[nb][reg] += xp[nb * 16 + reg];
    den += xp[32];
    den += __shfl_xor(den, 32);  // combine hi-halves -> full row sum
    if (l < 32) den_lds[wq * 32 + m31] = 1.0f / den;
    // den_lds written+read by this same wave -> no barrier needed
    float* ob = out + ((size_t)b * LQ + qbase + wq * 32) * DIM;
#pragma unroll
    for (int nb = 0; nb < 2; ++nb) {
#pragma unroll
      for (int reg = 0; reg < 16; ++reg) {
        const int qr2 = (reg & 3) + 8 * (reg >> 2) + hi * 4;
        float inv = den_lds[wq * 32 + qr2];
        ob[qr2 * DIM + nb * 32 + m31] = acc_o[nb][reg] * inv;
      }
    }
  }
}

}  // namespace

extern "C" void kernel_launch(void* const* d_in, const int* in_sizes, int n_in,
                              void* d_out, int out_size, void* d_ws,
                              size_t ws_size, hipStream_t stream) {
  const float* q = (const float*)d_in[0];
  const float* k = (const float*)d_in[1];
  const float* v = (const float*)d_in[2];
  const uint32_t* mask = (const uint32_t*)d_in[3];
  float* out = (float*)d_out;
  int* flag = (int*)d_ws;
  unsigned short* khi_f = (unsigned short*)((char*)d_ws + WS_KHI);
  unsigned short* klo_f = (unsigned short*)((char*)d_ws + WS_KLO);
  unsigned short* vt_f = (unsigned short*)((char*)d_ws + WS_VT);

  detect_mask_dtype<<<1, 256, 0, stream>>>(mask, flag);
  prep_k<<<2048, 256, 0, stream>>>(k, khi_f, klo_f);
  prep_v<<<512, 256, 0, stream>>>(v, vt_f);
  attn_mfma<<<dim3(512), 256, 0, stream>>>(q, khi_f, klo_f, vt_f, mask, flag,
                                           out);
}

// Round 9
// 168.387 us; speedup vs baseline: 1.2817x; 1.2817x over previous
//
#include <hip/hip_runtime.h>
#include <stdint.h>

namespace {

typedef short bf16x8 __attribute__((ext_vector_type(8)));
typedef float f32x16 __attribute__((ext_vector_type(16)));
typedef unsigned short u16x4 __attribute__((ext_vector_type(4)));

constexpr int BATCH = 16;
constexpr int LQ = 2048;
constexpr int LK = 2048;
constexpr int DIM = 64;
constexpr float SCALE = 0.125f;  // 1/sqrt(64)

// d_ws byte offsets (flag at 0) -- 13 MB total, proven available (R7/R8)
constexpr size_t WS_KHI = 1ull << 20;  // 4 MB bf16 K-hi, fragment-ordered
constexpr size_t WS_KLO = 5ull << 20;  // 4 MB bf16 K-lo
constexpr size_t WS_VT = 9ull << 20;   // 4 MB bf16 V, fragment-ordered

__global__ void detect_mask_dtype(const uint32_t* __restrict__ mask,
                                  int* __restrict__ flag) {
  __shared__ int bad;
  if (threadIdx.x == 0) bad = 0;
  __syncthreads();
  int my = 0;
  for (int i = threadIdx.x; i < 4096; i += 256) {
    uint32_t w = mask[i];
    if (w > 1u && w != 0x3F800000u) my = 1;
  }
  if (my) atomicOr(&bad, 1);
  __syncthreads();
  if (threadIdx.x == 0) *flag = bad;  // 1 -> uint8-packed
}

__device__ inline unsigned short f2bf(float x) {  // RNE fp32->bf16
  union { float f; unsigned u; } c;
  c.f = x;
  unsigned r = c.u + 0x7FFFu + ((c.u >> 16) & 1u);
  return (unsigned short)(r >> 16);
}
__device__ inline float bf2f(unsigned short h) {
  union { float f; unsigned u; } c;
  c.u = (unsigned)h << 16;
  return c.f;
}
__device__ inline int cvt_pk_bf16(float lo, float hi) {
  int d;
  asm("v_cvt_pk_bf16_f32 %0, %1, %2" : "=v"(d) : "v"(lo), "v"(hi));
  return d;
}

// mfma_f32_32x32x16_bf16: A m=l&31 k=(l>>5)*8+e; B n=l&31 same k;
// C/D col n=l&31, row m=(reg&3)+8*(reg>>2)+4*(l>>5)   [verified m74/m101; R8 PASS]

// K -> fragment-ordered [b][T][f][s][lane][8]; lane=hi*32+m, d=s*16+hi*8+e,
// k-row = T*64+f*32+m.   (verified by R8 PASS)
__global__ __launch_bounds__(256) void prep_k(const float* __restrict__ kp,
                                              unsigned short* __restrict__ khi,
                                              unsigned short* __restrict__ klo) {
  int idx = blockIdx.x * 256 + threadIdx.x;
  int b = idx >> 15;
  int rem = idx & 32767;
  int r = rem >> 4;
  int d0 = (rem & 15) * 4;
  float4 kf = *(const float4*)(kp + ((size_t)b * LK + r) * DIM + d0);
  u16x4 hv, lv;
#pragma unroll
  for (int j = 0; j < 4; ++j) {
    float x = (&kf.x)[j];
    unsigned short hh = f2bf(x);
    hv[j] = hh;
    lv[j] = f2bf(x - bf2f(hh));
  }
  int T = r >> 6;
  int rin = r & 63;
  int f = rin >> 5;
  int m = rin & 31;
  int s = d0 >> 4;
  int hi = (d0 >> 3) & 1;
  int e0 = d0 & 7;
  size_t off =
      ((((size_t)(b * 32 + T) * 2 + f) * 4 + s) * 64 + (hi * 32 + m)) * 8 + e0;
  *(u16x4*)(khi + off) = hv;
  *(u16x4*)(klo + off) = lv;
}

// V -> fragment-ordered [b][T][nb][ks][lane][8]; lane=hi*32+(d&31),
// k-in = ks*16+hi*8+e, d = nb*32+(d&31).   (verified by R8 PASS)
__global__ __launch_bounds__(256) void prep_v(const float* __restrict__ vp,
                                              unsigned short* __restrict__ vt) {
  int idx = blockIdx.x * 256 + threadIdx.x;
  int b = idx >> 13;
  int rem = idx & 8191;
  int kq = rem >> 4;
  int dq = rem & 15;
  int k0 = kq * 4;
  int T = k0 >> 6;
  int kin = k0 & 63;
  const float* vg = vp + ((size_t)b * LK + k0) * DIM + dq * 4;
  unsigned short tmp[4][4];
#pragma unroll
  for (int j = 0; j < 4; ++j) {
    float4 vf = *(const float4*)(vg + j * DIM);
#pragma unroll
    for (int i2 = 0; i2 < 4; ++i2) tmp[j][i2] = f2bf((&vf.x)[i2]);
  }
  int ks = kin >> 4;
  int hi = (kin >> 3) & 1;
  int e0 = kin & 7;
#pragma unroll
  for (int j2 = 0; j2 < 4; ++j2) {
    int d = dq * 4 + j2;
    int nb = d >> 5;
    u16x4 od = {tmp[0][j2], tmp[1][j2], tmp[2][j2], tmp[3][j2]};
    size_t off = ((((size_t)(b * 32 + T) * 2 + nb) * 4 + ks) * 64 +
                  (hi * 32 + (d & 31))) * 8 + e0;
    *(u16x4*)(vt + off) = od;
  }
}

// Main: 1024 blocks x 256 thr. Block = 32 q-rows; 4 waves = 4 k-quarters.
// Phase 0: block packs its own mask rows (256 KB raw -> 8 KB bits in LDS)
// at full HBM BW (64 deep-pipelined dwordx4/thread, all blocks co-resident).
// Compute: barrier-free; K/V fragment-ordered from L2; mask = 1 u64 LDS
// read per tile. No spillable arrays (named vectors only).
__global__ __launch_bounds__(256, 4) void attn_mfma(
    const float* __restrict__ qp, const unsigned short* __restrict__ khi_f,
    const unsigned short* __restrict__ klo_f,
    const unsigned short* __restrict__ vt_f,
    const uint32_t* __restrict__ maskp, const int* __restrict__ flagp,
    float* __restrict__ out) {
  // arena: phase0/compute = MbT u64[32 T][32 row] (8 KB);
  // epilogue (after barrier) = X float[3][64][33] (25.3 KB). Aliased.
  __shared__ __align__(16) unsigned char arena[3 * 64 * 33 * 4];
  __shared__ float den_s[32];
  unsigned long long* MbT = (unsigned long long*)arena;
  float* X = (float*)arena;

  const int tid = threadIdx.x;
  const int h = tid >> 6;  // k-quarter
  const int l = tid & 63;
  const int m31 = l & 31;
  const int hi = l >> 5;
  // XCD swizzle: 1024 blocks, 8 XCDs -> 2 batches/XCD (K/V frags L2-resident)
  const int xcd = blockIdx.x & 7;
  const int idx = blockIdx.x >> 3;  // 0..127
  const int b = xcd * 2 + (idx >> 6);
  const int qbase = (idx & 63) * 32;
  const int isU8 = *flagp;
  const int qrow = qbase + m31;

  // ---- phase 0: pack mask rows -> MbT[T][row] ----
  {
    const int prow = tid >> 3;  // 0..31
    const int pch = tid & 7;    // 256-col chunk
    if (!isU8) {
      const uint32_t* mg =
          maskp + ((size_t)b * LQ + qbase + prow) * LK + pch * 256;
      for (int T4 = 0; T4 < 4; ++T4) {
        uint4 x[16];
#pragma unroll
        for (int i = 0; i < 16; ++i)
          x[i] = *(const uint4*)(mg + T4 * 64 + i * 4);
        unsigned long long bits = 0;
#pragma unroll
        for (int i = 0; i < 16; ++i) {
          unsigned nib = (unsigned)(x[i].x != 0u) |
                         ((unsigned)(x[i].y != 0u) << 1) |
                         ((unsigned)(x[i].z != 0u) << 2) |
                         ((unsigned)(x[i].w != 0u) << 3);
          bits |= (unsigned long long)nib << (4 * i);
        }
        MbT[(pch * 4 + T4) * 32 + prow] = bits;
      }
    } else {
      const uint8_t* mg = (const uint8_t*)maskp +
                          ((size_t)b * LQ + qbase + prow) * LK + pch * 256;
      for (int T4 = 0; T4 < 4; ++T4) {
        uint4 x[4];
#pragma unroll
        for (int i = 0; i < 4; ++i)
          x[i] = *(const uint4*)(mg + T4 * 64 + i * 16);
        unsigned long long bits = 0;
#pragma unroll
        for (int i = 0; i < 4; ++i) {
#pragma unroll
          for (int dd = 0; dd < 4; ++dd) {
            uint32_t wv = (&x[i].x)[dd];
            unsigned nib = (unsigned)((wv & 0xFFu) != 0u) |
                           ((unsigned)(((wv >> 8) & 0xFFu) != 0u) << 1) |
                           ((unsigned)(((wv >> 16) & 0xFFu) != 0u) << 2) |
                           ((unsigned)(((wv >> 24) & 0xFFu) != 0u) << 3);
            bits |= (unsigned long long)nib << (i * 16 + dd * 4);
          }
        }
        MbT[(pch * 4 + T4) * 32 + prow] = bits;
      }
    }
  }
  __syncthreads();

  // ---- Q fragments (hi/lo split), B-operand ----
  bf16x8 qh[4], ql[4];
  {
    const float* qr = qp + ((size_t)b * LQ + qrow) * DIM;
#pragma unroll
    for (int s = 0; s < 4; ++s) {
#pragma unroll
      for (int j2 = 0; j2 < 2; ++j2) {
        float4 x = *(const float4*)(qr + s * 16 + hi * 8 + j2 * 4);
#pragma unroll
        for (int j = 0; j < 4; ++j) {
          float xv = (&x.x)[j];
          unsigned short hh = f2bf(xv);
          qh[s][j2 * 4 + j] = (short)hh;
          ql[s][j2 * 4 + j] = (short)f2bf(xv - bf2f(hh));
        }
      }
    }
  }

  f32x16 oA = (f32x16)(0.f), oB = (f32x16)(0.f);
  float den = 0.f;

  for (int t = 0; t < 8; ++t) {
    const int T = h * 8 + t;
    const unsigned long long mb = MbT[T * 32 + m31];
    const uint32_t b0 = (uint32_t)mb;          // tile cols 0..31  (f=0)
    const uint32_t b1 = (uint32_t)(mb >> 32);  // tile cols 32..63 (f=1)

    // ---- swapped QK^T: S^T = K*Q^T, 3-term split, dual chains ----
    f32x16 sA = (f32x16)(0.f), sB = (f32x16)(0.f);
#pragma unroll
    for (int s = 0; s < 4; ++s) {
      const size_t o0 =
          ((((size_t)(b * 32 + T) * 2 + 0) * 4 + s) * 64 + l) * 8;
      const size_t o1 =
          ((((size_t)(b * 32 + T) * 2 + 1) * 4 + s) * 64 + l) * 8;
      bf16x8 k0h = *(const bf16x8*)(khi_f + o0);
      bf16x8 k0l = *(const bf16x8*)(klo_f + o0);
      bf16x8 k1h = *(const bf16x8*)(khi_f + o1);
      bf16x8 k1l = *(const bf16x8*)(klo_f + o1);
      sA = __builtin_amdgcn_mfma_f32_32x32x16_bf16(k0h, qh[s], sA, 0, 0, 0);
      sB = __builtin_amdgcn_mfma_f32_32x32x16_bf16(k1h, qh[s], sB, 0, 0, 0);
      sA = __builtin_amdgcn_mfma_f32_32x32x16_bf16(k0l, qh[s], sA, 0, 0, 0);
      sB = __builtin_amdgcn_mfma_f32_32x32x16_bf16(k1l, qh[s], sB, 0, 0, 0);
      sA = __builtin_amdgcn_mfma_f32_32x32x16_bf16(k0h, ql[s], sA, 0, 0, 0);
      sB = __builtin_amdgcn_mfma_f32_32x32x16_bf16(k1h, ql[s], sB, 0, 0, 0);
    }

    // ---- mask + exp in-register ----
    const int hi4 = hi * 4;
#pragma unroll
    for (int reg = 0; reg < 16; ++reg) {
      const int crow = (reg & 3) + 8 * (reg >> 2);
      float eA = ((b0 >> (crow + hi4)) & 1u) ? 1.0f : __expf(sA[reg] * SCALE);
      float eB = ((b1 >> (crow + hi4)) & 1u) ? 1.0f : __expf(sB[reg] * SCALE);
      den += eA + eB;
      sA[reg] = eA;
      sB[reg] = eB;
    }

    // ---- P->A frags (cvt_pk + permlane32_swap, R8-verified) + PV ----
#define PV_STEP(SV, A_, KS_)                                                  \
  do {                                                                        \
    int c0x = cvt_pk_bf16(SV[8 * A_ + 0], SV[8 * A_ + 1]);                    \
    int c1x = cvt_pk_bf16(SV[8 * A_ + 2], SV[8 * A_ + 3]);                    \
    int c0y = cvt_pk_bf16(SV[8 * A_ + 4], SV[8 * A_ + 5]);                    \
    int c1y = cvt_pk_bf16(SV[8 * A_ + 6], SV[8 * A_ + 7]);                    \
    asm("v_permlane32_swap_b32 %0, %1" : "+v"(c0x), "+v"(c0y));               \
    asm("v_permlane32_swap_b32 %0, %1" : "+v"(c1x), "+v"(c1y));               \
    union { int d[4]; bf16x8 v; } pa_;                                        \
    pa_.d[0] = c0x; pa_.d[1] = c1x; pa_.d[2] = c0y; pa_.d[3] = c1y;           \
    const size_t vo0 =                                                        \
        ((((size_t)(b * 32 + T) * 2 + 0) * 4 + KS_) * 64 + l) * 8;            \
    const size_t vo1 =                                                        \
        ((((size_t)(b * 32 + T) * 2 + 1) * 4 + KS_) * 64 + l) * 8;            \
    bf16x8 vb0 = *(const bf16x8*)(vt_f + vo0);                                \
    bf16x8 vb1 = *(const bf16x8*)(vt_f + vo1);                                \
    oA = __builtin_amdgcn_mfma_f32_32x32x16_bf16(pa_.v, vb0, oA, 0, 0, 0);    \
    oB = __builtin_amdgcn_mfma_f32_32x32x16_bf16(pa_.v, vb1, oB, 0, 0, 0);    \
  } while (0)

    PV_STEP(sA, 0, 0);
    PV_STEP(sA, 1, 1);
    PV_STEP(sB, 0, 2);
    PV_STEP(sB, 1, 3);
#undef PV_STEP
  }

  // ---- epilogue: combine 4 k-quarters ----
  __syncthreads();  // all compute done; arena becomes X
  if (h > 0) {
    float* xp = X + ((size_t)((h - 1) * 64 + l)) * 33;
#pragma unroll
    for (int reg = 0; reg < 16; ++reg) {
      xp[reg] = oA[reg];
      xp[16 + reg] = oB[reg];
    }
    xp[32] = den;
  }
  __syncthreads();
  if (h == 0) {
#pragma unroll
    for (int p = 0; p < 3; ++p) {
      const float* xp = X + ((size_t)(p * 64 + l)) * 33;
#pragma unroll
      for (int reg = 0; reg < 16; ++reg) {
        oA[reg] += xp[reg];
        oB[reg] += xp[16 + reg];
      }
      den += xp[32];
    }
    den += __shfl_xor(den, 32);  // combine hi halves -> full row sum
    if (l < 32) den_s[m31] = 1.0f / den;
    // den_s written+read by this same wave; compiler orders via lgkmcnt
    float* ob = out + ((size_t)b * LQ + qbase) * DIM;
#pragma unroll
    for (int reg = 0; reg < 16; ++reg) {
      const int qr2 = (reg & 3) + 8 * (reg >> 2) + hi * 4;
      const float inv = den_s[qr2];
      ob[qr2 * DIM + m31] = oA[reg] * inv;
      ob[qr2 * DIM + 32 + m31] = oB[reg] * inv;
    }
  }
}

}  // namespace

extern "C" void kernel_launch(void* const* d_in, const int* in_sizes, int n_in,
                              void* d_out, int out_size, void* d_ws,
                              size_t ws_size, hipStream_t stream) {
  const float* q = (const float*)d_in[0];
  const float* k = (const float*)d_in[1];
  const float* v = (const float*)d_in[2];
  const uint32_t* mask = (const uint32_t*)d_in[3];
  float* out = (float*)d_out;
  int* flag = (int*)d_ws;
  unsigned short* khi_f = (unsigned short*)((char*)d_ws + WS_KHI);
  unsigned short* klo_f = (unsigned short*)((char*)d_ws + WS_KLO);
  unsigned short* vt_f = (unsigned short*)((char*)d_ws + WS_VT);

  detect_mask_dtype<<<1, 256, 0, stream>>>(mask, flag);
  prep_k<<<2048, 256, 0, stream>>>(k, khi_f, klo_f);
  prep_v<<<512, 256, 0, stream>>>(v, vt_f);
  attn_mfma<<<dim3(1024), 256, 0, stream>>>(q, khi_f, klo_f, vt_f, mask, flag,
                                            out);
}